// Round 3
// baseline (45.085 us; speedup 1.0000x reference)
//
#include <hip/hip_runtime.h>
#include <math.h>

#define B_SZ 4096
#define D_SZ 32
#define M1_SZ 8
#define H_SZ 64
#define NSTEP 20
#define S1 21
#define BROWS 64   // batch rows per block
#define BT 256     // 4 waves; lane = [q(2b)|b_lo(4b)], wave covers 16 rows
#define HQ 16      // h values per thread (64 / 4 quarters)

#ifndef M_PI
#define M_PI 3.14159265358979323846
#endif

#define LOG2E 1.44269504088896340736f
#define LN2   0.69314718055994530942f

__device__ __forceinline__ float fast_exp2(float x) {
#if __has_builtin(__builtin_amdgcn_exp2f)
  return __builtin_amdgcn_exp2f(x);
#else
  return exp2f(x);
#endif
}

__device__ __forceinline__ float fast_rcp(float x) {
#if __has_builtin(__builtin_amdgcn_rcpf)
  return __builtin_amdgcn_rcpf(x);
#else
  return 1.0f / x;
#endif
}

__global__ __launch_bounds__(BT) void umnn_main_kernel(
    const float* __restrict__ x, const float* __restrict__ x0,
    const float* __restrict__ We, const float* __restrict__ be,
    const float* __restrict__ W1, const float* __restrict__ b1,
    const float* __restrict__ W2, const float* __restrict__ b2,
    const float* __restrict__ scaling, float* __restrict__ out) {
  const int btile = blockIdx.x * BROWS;
  const int d = blockIdx.y;  // block-uniform
  const int tid = threadIdx.x;

  __shared__ float W1t[H_SZ * 12];   // [h][i], i=0..8, stride 12 (48B aligned)
  __shared__ float b1s[H_SZ];
  __shared__ float W2s[H_SZ];
  __shared__ float Wes[D_SZ * M1_SZ];  // c-major [c][m]
  __shared__ float bes[M1_SZ];
  __shared__ float ccws[S1];
  __shared__ float stepss[S1];
  __shared__ float misc[2];            // b2[d], exp(scaling[d])
  __shared__ float xs[BROWS * 36];     // x tile, row stride 36

  // ---- staging ----
  {
    const float* W1d = W1 + d * (M1_SZ + 1) * H_SZ;  // [i][h] row-major
    for (int idx = tid; idx < (M1_SZ + 1) * H_SZ; idx += BT) {
      int i = idx >> 6, h = idx & 63;    // coalesced global read
      W1t[h * 12 + i] = W1d[idx];        // transposed LDS write
    }
    if (tid < H_SZ) { b1s[tid] = b1[d * H_SZ + tid]; W2s[tid] = W2[d * H_SZ + tid]; }
    if (tid < M1_SZ) bes[tid] = be[tid * D_SZ + d];
    {
      int m = tid >> 5, c = tid & 31;
      Wes[c * M1_SZ + m] = We[(m * D_SZ + d) * D_SZ + c];
    }
    const float4* xg = reinterpret_cast<const float4*>(x + (size_t)btile * D_SZ);
#pragma unroll
    for (int k = 0; k < 2; ++k) {
      int i4 = tid + k * BT;
      int row = i4 >> 3, c4 = i4 & 7;
      *reinterpret_cast<float4*>(&xs[row * 36 + c4 * 4]) = xg[i4];
    }
    if (tid < S1) {  // fp32 Clenshaw-Curtis (threshold is lenient)
      stepss[tid] = cosf((float)tid * ((float)M_PI / 20.f));
      float acc = 0.f;
#pragma unroll
      for (int k = 0; k <= 10; ++k) {
        float w = (k == 0) ? 1.f : 2.f / (1.f - 4.f * (float)(k * k));
        float c = cosf((float)(k * tid) * ((float)M_PI / 10.f));
        float lam = (tid == 0 || tid == NSTEP) ? 0.5f * c : c;
        acc += w * lam;
      }
      ccws[tid] = 0.1f * acc;
    }
    if (tid == 0) { misc[0] = b2[d]; misc[1] = __expf(scaling[d]); }
  }
  __syncthreads();

  const int lane = tid & 63;
  const int q = lane >> 4;                           // h-quarter
  const int b_local = ((tid >> 6) << 4) | (lane & 15);
  const int b = btile + b_local;
  const float* xrow = &xs[b_local * 36];

  // ---- masked encoder ----
  float a[M1_SZ];
#pragma unroll
  for (int m = 0; m < M1_SZ; ++m) a[m] = bes[m];
  for (int c = 0; c < d; ++c) {  // wave-uniform trip count
    float xc = xrow[c];
#pragma unroll
    for (int m = 0; m < M1_SZ; ++m) a[m] = fmaf(xc, Wes[c * M1_SZ + m], a[m]);
  }
  float hm[M1_SZ];
#pragma unroll
  for (int m = 0; m < M1_SZ; ++m) {  // tanh via exp2 + rcp
    float t = fast_exp2(a[m] * (2.f * LOG2E));
    hm[m] = 1.f - 2.f * fast_rcp(t + 1.f);
  }
  const float hm0 = hm[0];

  const float xb = xrow[d];
  const float x0b = x0[(size_t)b * D_SZ + d];
  const float dxe = xb - x0b;
  const float xc1 = 0.5f * dxe;
  const float xc1L = xc1 * LOG2E;
  const float xc0L = (x0b + xc1) * LOG2E;

  // ---- preload per-h constants (16 h per thread) ----
  float baseL[HQ], w1x[HQ], w2h[HQ];
  float w2sA = 0.f, w2sB = 0.f;
#pragma unroll
  for (int j = 0; j < HQ; ++j) {
    const int hh = q * HQ + j;
    const float* wrow = &W1t[hh * 12];
    float base = b1s[hh];
#pragma unroll
    for (int m = 0; m < M1_SZ; ++m) base = fmaf(hm[m], wrow[m + 1], base);
    baseL[j] = base * LOG2E;
    w1x[j] = wrow[0];
    w2h[j] = W2s[hh];
    if (j & 1) w2sB += w2h[j]; else w2sA += w2h[j];
  }
  const float b2v = misc[0];

  // ---- fused main loop: per step, 16-h partial -> butterfly -> elu -> dzsum ----
  float dzsum = 0.f;
#pragma unroll
  for (int s = 0; s < S1; ++s) {
    const float XsL = fmaf(xc1L, stepss[s], xc0L);
    float accA = -w2sA, accB = -w2sB;  // folds the elu "-1" term
#pragma unroll
    for (int j = 0; j < HQ; j += 2) {
      {
        float preL = fmaf(XsL, w1x[j], baseL[j]);
        float e = fmaf(fmaxf(preL, 0.f), LN2, fast_exp2(fminf(preL, 0.f)));
        accA = fmaf(e, w2h[j], accA);
      }
      {
        float preL = fmaf(XsL, w1x[j + 1], baseL[j + 1]);
        float e = fmaf(fmaxf(preL, 0.f), LN2, fast_exp2(fminf(preL, 0.f)));
        accB = fmaf(e, w2h[j + 1], accB);
      }
    }
    float acc = accA + accB;
    acc += __shfl_xor(acc, 16);
    acc += __shfl_xor(acc, 32);
    acc += b2v;
    float pL = acc * LOG2E;
    float dz = fmaf(fmaxf(pL, 0.f), LN2, fast_exp2(fminf(pL, 0.f)));  // elu+1
    dzsum = fmaf(ccws[s], dz, dzsum);
  }

  float z = fmaf(xc1, dzsum, hm0);  // z_int + z0
  if (q == 0) out[(size_t)b * D_SZ + d] = misc[1] * z;
}

extern "C" void kernel_launch(void* const* d_in, const int* in_sizes, int n_in,
                              void* d_out, int out_size, void* d_ws, size_t ws_size,
                              hipStream_t stream) {
  const float* x       = (const float*)d_in[0];
  const float* x0      = (const float*)d_in[1];
  const float* We      = (const float*)d_in[2];
  const float* be      = (const float*)d_in[3];
  const float* W1      = (const float*)d_in[4];
  const float* b1      = (const float*)d_in[5];
  const float* W2      = (const float*)d_in[6];
  const float* b2      = (const float*)d_in[7];
  const float* scaling = (const float*)d_in[8];
  float* out = (float*)d_out;

  dim3 grid(B_SZ / BROWS, D_SZ);
  umnn_main_kernel<<<grid, BT, 0, stream>>>(x, x0, We, be, W1, b1, W2, b2,
                                            scaling, out);
}